// Round 1
// baseline (3289.594 us; speedup 1.0000x reference)
//
#include <hip/hip_runtime.h>
#include <hip/hip_bf16.h>
#include <cstdint>

// Shapes (fixed by the problem)
#define NB 32
#define NS 1024
#define NH 768
#define NP 98

// ---------------------------------------------------------------------------
// K1: scores[b,s] = dot(hidden[b,s,:], attn_w) + attn_b   (one wave per row)
// ---------------------------------------------------------------------------
__global__ void k_scores(const float* __restrict__ hidden, const float* __restrict__ aw,
                         const float* __restrict__ ab, float* __restrict__ scores) {
  int row = blockIdx.x * 4 + (threadIdx.x >> 6);
  int lane = threadIdx.x & 63;
  const float* x = hidden + (size_t)row * NH;
  float acc = 0.f;
#pragma unroll
  for (int i = 0; i < 3; ++i) {
    float4 xv = *(const float4*)(x + i * 256 + lane * 4);
    float4 wv = *(const float4*)(aw + i * 256 + lane * 4);
    acc += xv.x * wv.x + xv.y * wv.y + xv.z * wv.z + xv.w * wv.w;
  }
#pragma unroll
  for (int off = 32; off; off >>= 1) acc += __shfl_xor(acc, off);
  if (lane == 0) scores[row] = acc + ab[0];
}

// ---------------------------------------------------------------------------
// K2: per-batch cue_len, softmax max m[b] and denom l[b] over valid prefix
// ---------------------------------------------------------------------------
__global__ void k_stats(const int* __restrict__ mask, const float* __restrict__ scores,
                        int* __restrict__ cue, float* __restrict__ mout,
                        float* __restrict__ lout) {
  int b = blockIdx.x, t = threadIdx.x;
  int lane = t & 63, w = t >> 6;
  __shared__ float red[4];
  __shared__ int redi[4];
  __shared__ int cue_s;

  int sm = 0;
#pragma unroll
  for (int i = 0; i < 4; ++i) sm += mask[b * NS + t + 256 * i];
#pragma unroll
  for (int off = 32; off; off >>= 1) sm += __shfl_xor(sm, off);
  if (lane == 0) redi[w] = sm;
  __syncthreads();
  if (t == 0) {
    int tot = redi[0] + redi[1] + redi[2] + redi[3];
    tot = min(max(tot, 1), NS);
    cue_s = tot;
    cue[b] = tot;
  }
  __syncthreads();
  int cl = cue_s;

  float mx = -1e30f;
#pragma unroll
  for (int i = 0; i < 4; ++i) {
    int s = t + 256 * i;
    if (s < cl) mx = fmaxf(mx, scores[b * NS + s]);
  }
#pragma unroll
  for (int off = 32; off; off >>= 1) mx = fmaxf(mx, __shfl_xor(mx, off));
  if (lane == 0) red[w] = mx;
  __syncthreads();
  float m = fmaxf(fmaxf(red[0], red[1]), fmaxf(red[2], red[3]));
  __syncthreads();  // red[] reused below

  float sum = 0.f;
#pragma unroll
  for (int i = 0; i < 4; ++i) {
    int s = t + 256 * i;
    if (s < cl) sum += __expf(scores[b * NS + s] - m);
  }
#pragma unroll
  for (int off = 32; off; off >>= 1) sum += __shfl_xor(sum, off);
  if (lane == 0) red[w] = sum;
  __syncthreads();
  if (t == 0) {
    mout[b] = m;
    lout[b] = red[0] + red[1] + red[2] + red[3];
  }
}

// ---------------------------------------------------------------------------
// K3: s_x[b,h] = sum_s attn[b,s] * hidden[b,s,h]  (64-s chunks, atomicAdd)
// grid (16 chunks, 32 batches), block 256. sx must be pre-zeroed.
// ---------------------------------------------------------------------------
__global__ void k_sx(const float* __restrict__ hidden, const float* __restrict__ scores,
                     const int* __restrict__ cue, const float* __restrict__ m,
                     const float* __restrict__ l, float* __restrict__ sx) {
  int b = blockIdx.y, ch = blockIdx.x, t = threadIdx.x;
  int s0 = ch * 64;
  int cl = cue[b];
  if (s0 >= cl) return;  // fully-invalid chunk: contributes 0
  __shared__ float w[64];
  if (t < 64) {
    int s = s0 + t;
    float wv = 0.f;
    if (s < cl) wv = __expf(scores[b * NS + s] - m[b]) / l[b];
    w[t] = wv;
  }
  __syncthreads();
  float a0 = 0.f, a1 = 0.f, a2 = 0.f;
  const float* base = hidden + ((size_t)(b * NS + s0)) * NH;
  for (int s = 0; s < 64; ++s) {
    float ws = w[s];
    const float* r = base + s * NH;
    a0 = fmaf(ws, r[t], a0);
    a1 = fmaf(ws, r[t + 256], a1);
    a2 = fmaf(ws, r[t + 512], a2);
  }
  atomicAdd(&sx[b * NH + t], a0);
  atomicAdd(&sx[b * NH + t + 256], a1);
  atomicAdd(&sx[b * NH + t + 512], a2);
}

// ---------------------------------------------------------------------------
// K4: g1[b,o] = dot(s_x[b,:], gate_w[o, 0:768])   (wave per o, 32 blocks)
// ---------------------------------------------------------------------------
__global__ void k_g1(const float* __restrict__ sx, const float* __restrict__ gate_w,
                     float* __restrict__ g1) {
  int b = blockIdx.x, t = threadIdx.x;
  __shared__ float sl[NH];
#pragma unroll
  for (int i = 0; i < 3; ++i) sl[t + 256 * i] = sx[b * NH + t + 256 * i];
  __syncthreads();
  int w = t >> 6, lane = t & 63;
  for (int o = w; o < NH; o += 4) {
    const float* gr = gate_w + (size_t)o * (2 * NH);
    float acc = 0.f;
#pragma unroll
    for (int j = 0; j < 3; ++j) {
      float4 gv = *(const float4*)(gr + j * 256 + lane * 4);
      float4 sv = *(const float4*)(&sl[j * 256 + lane * 4]);
      acc += gv.x * sv.x + gv.y * sv.y + gv.z * sv.z + gv.w * sv.w;
    }
#pragma unroll
    for (int off = 32; off; off >>= 1) acc += __shfl_xor(acc, off);
    if (lane == 0) g1[b * NH + o] = acc;
  }
}

// ---------------------------------------------------------------------------
// K5: fused main kernel. Per block: 16 rows (one batch) x full 768 width.
//   phase A: stage x tile (16x768 f32) in LDS
//   phase B: g2 = x @ gate_wh^T, BK=16 slabs of gate_wh staged in LDS
//   phase C: elementwise gate -> hs, overwrite x tile in place
//   phase D: out = clip(sigmoid(hs @ lin_w^T + lin_b))
// LDS: xt 16x772 f32 (49.4KB, stride 772 breaks 768%32==0 bank aliasing)
//      bsl 768x20 f32 (61.4KB, stride 20 spreads b128 reads across banks)
// ---------------------------------------------------------------------------
__global__ __launch_bounds__(256, 1) void k_main(
    const float* __restrict__ hidden, const float* __restrict__ gate_w,
    const float* __restrict__ gate_b, const float* __restrict__ lin_w,
    const float* __restrict__ lin_b, const float* __restrict__ sx,
    const float* __restrict__ g1, const int* __restrict__ cue,
    float* __restrict__ out) {
  __shared__ float xt[16][772];
  __shared__ float bsl[768][20];
  int t = threadIdx.x;
  int row0 = blockIdx.x * 16;
  int b = row0 >> 10;
  int s0 = row0 & 1023;

  // phase A: stage x tile (coalesced float4)
  const float* src = hidden + (size_t)row0 * NH;
#pragma unroll
  for (int i = 0; i < 12; ++i) {
    int e = (t + 256 * i) * 4;
    int r = e / NH, c = e % NH;
    *(float4*)&xt[r][c] = *(const float4*)(src + e);
  }

  float acc[4][12];
#pragma unroll
  for (int r = 0; r < 4; ++r)
#pragma unroll
    for (int j = 0; j < 12; ++j) acc[r][j] = 0.f;

  int rg = t >> 6, lane = t & 63;
  int os = t >> 2, q = t & 3;

  // phase B: g2 GEMM over 48 K-slabs of 16
  for (int slab = 0; slab < 48; ++slab) {
    int k0 = slab * 16;
    // stage gate_wh[:, k0:k0+16] -> bsl (each 64B global read = one full line)
#pragma unroll
    for (int p = 0; p < 12; ++p) {
      int oo = os + 64 * p;
      *(float4*)&bsl[oo][q * 4] =
          *(const float4*)(gate_w + (size_t)oo * (2 * NH) + NH + k0 + q * 4);
    }
    __syncthreads();
#pragma unroll
    for (int kq = 0; kq < 4; ++kq) {
      float4 a[4];
#pragma unroll
      for (int r = 0; r < 4; ++r)
        a[r] = *(const float4*)&xt[rg * 4 + r][k0 + kq * 4];  // wave-uniform bcast
#pragma unroll
      for (int j = 0; j < 12; ++j) {
        float4 bv = *(const float4*)&bsl[lane + 64 * j][kq * 4];
#pragma unroll
        for (int r = 0; r < 4; ++r)
          acc[r][j] += a[r].x * bv.x + a[r].y * bv.y + a[r].z * bv.z + a[r].w * bv.w;
      }
    }
    __syncthreads();  // protect bsl overwrite next slab (also fences last slab)
  }

  // phase C: elementwise gate; overwrite xt with hs (each (row,o) single owner)
  int cl = cue[b];
#pragma unroll
  for (int j = 0; j < 12; ++j) {
    int o = lane + 64 * j;
    float g1v = g1[b * NH + o];
    float gbv = gate_b[o];
    float sxv = sx[b * NH + o];
#pragma unroll
    for (int r = 0; r < 4; ++r) {
      int row = rg * 4 + r;
      float x = xt[row][o];
      float gl = g1v + acc[r][j] + gbv;
      float g = 1.f / (1.f + __expf(-gl));
      float fused = g * sxv + (1.f - g) * x;
      float hs = x + (((s0 + row) < cl) ? fused : 0.f);
      xt[row][o] = hs;
    }
  }
  __syncthreads();

  // phase D: lin head. thread t -> row = t&15, p = (t>>4) + 16*i
  int rowl = t & 15;
  int pb = t >> 4;
  float accv[7];
#pragma unroll
  for (int i = 0; i < 7; ++i) accv[i] = 0.f;
  for (int oq = 0; oq < 192; ++oq) {
    float4 h = *(const float4*)&xt[rowl][oq * 4];
#pragma unroll
    for (int i = 0; i < 7; ++i) {
      int p = pb + 16 * i;
      if (p < NP) {
        float4 wv = *(const float4*)(lin_w + (size_t)p * NH + oq * 4);
        accv[i] += h.x * wv.x + h.y * wv.y + h.z * wv.z + h.w * wv.w;
      }
    }
  }
#pragma unroll
  for (int i = 0; i < 7; ++i) {
    int p = pb + 16 * i;
    if (p < NP) {
      float v = accv[i] + lin_b[p];
      v = 1.f / (1.f + __expf(-v));
      v = fminf(fmaxf(v, 1e-7f), 1.f - 1e-7f);
      out[(size_t)(row0 + rowl) * NP + p] = v;
    }
  }
}

// ---------------------------------------------------------------------------
extern "C" void kernel_launch(void* const* d_in, const int* in_sizes, int n_in,
                              void* d_out, int out_size, void* d_ws, size_t ws_size,
                              hipStream_t stream) {
  const float* hidden = (const float*)d_in[0];
  // d_in[1] = batch_subject_ids: unused by the reference
  const int* mask = (const int*)d_in[2];
  const float* attn_w = (const float*)d_in[3];
  const float* attn_b = (const float*)d_in[4];
  const float* gate_w = (const float*)d_in[5];
  const float* gate_b = (const float*)d_in[6];
  const float* lin_w = (const float*)d_in[7];
  const float* lin_b = (const float*)d_in[8];
  float* out = (float*)d_out;

  // workspace layout (floats): [cue:32int][m:32][l:32][scores:32768][sx:24576][g1:24576]
  float* F = (float*)d_ws;
  int* cue = (int*)F;
  float* m = F + 32;
  float* l = F + 64;
  float* scores = F + 96;
  float* sx = scores + NB * NS;
  float* g1 = sx + NB * NH;

  hipMemsetAsync(sx, 0, NB * NH * sizeof(float), stream);  // K3 accumulates via atomics
  k_scores<<<(NB * NS) / 4, 256, 0, stream>>>(hidden, attn_w, attn_b, scores);
  k_stats<<<NB, 256, 0, stream>>>(mask, scores, cue, m, l);
  k_sx<<<dim3(16, NB), 256, 0, stream>>>(hidden, scores, cue, m, l, sx);
  k_g1<<<NB, 256, 0, stream>>>(sx, gate_w, g1);
  k_main<<<(NB * NS) / 16, 256, 0, stream>>>(hidden, gate_w, gate_b, lin_w, lin_b,
                                             sx, g1, cue, out);
}

// Round 2
// 510.917 us; speedup vs baseline: 6.4386x; 6.4386x over previous
//
#include <hip/hip_runtime.h>
#include <hip/hip_bf16.h>
#include <cstdint>

// Shapes (fixed by the problem)
#define NB 32
#define NS 1024
#define NH 768
#define NP 98

typedef __attribute__((ext_vector_type(8))) short short8;
typedef __attribute__((ext_vector_type(4))) float f32x4;

static __device__ __forceinline__ ushort f2bf(float f) {
  uint32_t u = __builtin_bit_cast(uint32_t, f);
  u += 0x7fff + ((u >> 16) & 1);  // RNE
  return (ushort)(u >> 16);
}
static __device__ __forceinline__ float bf2f(ushort h) {
  uint32_t u = ((uint32_t)h) << 16;
  return __builtin_bit_cast(float, u);
}

// ---------------------------------------------------------------------------
// K1: scores[b,s] = dot(hidden[b,s,:], attn_w) + attn_b   (one wave per row)
// ---------------------------------------------------------------------------
__global__ void k_scores(const float* __restrict__ hidden, const float* __restrict__ aw,
                         const float* __restrict__ ab, float* __restrict__ scores) {
  int row = blockIdx.x * 4 + (threadIdx.x >> 6);
  int lane = threadIdx.x & 63;
  const float* x = hidden + (size_t)row * NH;
  float acc = 0.f;
#pragma unroll
  for (int i = 0; i < 3; ++i) {
    float4 xv = *(const float4*)(x + i * 256 + lane * 4);
    float4 wv = *(const float4*)(aw + i * 256 + lane * 4);
    acc += xv.x * wv.x + xv.y * wv.y + xv.z * wv.z + xv.w * wv.w;
  }
#pragma unroll
  for (int off = 32; off; off >>= 1) acc += __shfl_xor(acc, off);
  if (lane == 0) scores[row] = acc + ab[0];
}

// ---------------------------------------------------------------------------
// K2: per-batch cue_len, softmax max m[b] and denom l[b] over valid prefix
// ---------------------------------------------------------------------------
__global__ void k_stats(const int* __restrict__ mask, const float* __restrict__ scores,
                        int* __restrict__ cue, float* __restrict__ mout,
                        float* __restrict__ lout) {
  int b = blockIdx.x, t = threadIdx.x;
  int lane = t & 63, w = t >> 6;
  __shared__ float red[4];
  __shared__ int redi[4];
  __shared__ int cue_s;

  int sm = 0;
#pragma unroll
  for (int i = 0; i < 4; ++i) sm += mask[b * NS + t + 256 * i];
#pragma unroll
  for (int off = 32; off; off >>= 1) sm += __shfl_xor(sm, off);
  if (lane == 0) redi[w] = sm;
  __syncthreads();
  if (t == 0) {
    int tot = redi[0] + redi[1] + redi[2] + redi[3];
    tot = min(max(tot, 1), NS);
    cue_s = tot;
    cue[b] = tot;
  }
  __syncthreads();
  int cl = cue_s;

  float mx = -1e30f;
#pragma unroll
  for (int i = 0; i < 4; ++i) {
    int s = t + 256 * i;
    if (s < cl) mx = fmaxf(mx, scores[b * NS + s]);
  }
#pragma unroll
  for (int off = 32; off; off >>= 1) mx = fmaxf(mx, __shfl_xor(mx, off));
  if (lane == 0) red[w] = mx;
  __syncthreads();
  float m = fmaxf(fmaxf(red[0], red[1]), fmaxf(red[2], red[3]));
  __syncthreads();  // red[] reused below

  float sum = 0.f;
#pragma unroll
  for (int i = 0; i < 4; ++i) {
    int s = t + 256 * i;
    if (s < cl) sum += __expf(scores[b * NS + s] - m);
  }
#pragma unroll
  for (int off = 32; off; off >>= 1) sum += __shfl_xor(sum, off);
  if (lane == 0) red[w] = sum;
  __syncthreads();
  if (t == 0) {
    mout[b] = m;
    lout[b] = red[0] + red[1] + red[2] + red[3];
  }
}

// ---------------------------------------------------------------------------
// K3: s_x[b,h] = sum_s attn[b,s] * hidden[b,s,h]  (64-s chunks, atomicAdd)
// ---------------------------------------------------------------------------
__global__ void k_sx(const float* __restrict__ hidden, const float* __restrict__ scores,
                     const int* __restrict__ cue, const float* __restrict__ m,
                     const float* __restrict__ l, float* __restrict__ sx) {
  int b = blockIdx.y, ch = blockIdx.x, t = threadIdx.x;
  int s0 = ch * 64;
  int cl = cue[b];
  if (s0 >= cl) return;  // fully-invalid chunk: contributes 0
  __shared__ float w[64];
  if (t < 64) {
    int s = s0 + t;
    float wv = 0.f;
    if (s < cl) wv = __expf(scores[b * NS + s] - m[b]) / l[b];
    w[t] = wv;
  }
  __syncthreads();
  float a0 = 0.f, a1 = 0.f, a2 = 0.f;
  const float* base = hidden + ((size_t)(b * NS + s0)) * NH;
  for (int s = 0; s < 64; ++s) {
    float ws = w[s];
    const float* r = base + s * NH;
    a0 = fmaf(ws, r[t], a0);
    a1 = fmaf(ws, r[t + 256], a1);
    a2 = fmaf(ws, r[t + 512], a2);
  }
  atomicAdd(&sx[b * NH + t], a0);
  atomicAdd(&sx[b * NH + t + 256], a1);
  atomicAdd(&sx[b * NH + t + 512], a2);
}

// ---------------------------------------------------------------------------
// K4: g1[b,o] = dot(s_x[b,:], gate_w[o, 0:768])   (wave per o, 32 blocks)
// ---------------------------------------------------------------------------
__global__ void k_g1(const float* __restrict__ sx, const float* __restrict__ gate_w,
                     float* __restrict__ g1) {
  int b = blockIdx.x, t = threadIdx.x;
  __shared__ float sl[NH];
#pragma unroll
  for (int i = 0; i < 3; ++i) sl[t + 256 * i] = sx[b * NH + t + 256 * i];
  __syncthreads();
  int w = t >> 6, lane = t & 63;
  for (int o = w; o < NH; o += 4) {
    const float* gr = gate_w + (size_t)o * (2 * NH);
    float acc = 0.f;
#pragma unroll
    for (int j = 0; j < 3; ++j) {
      float4 gv = *(const float4*)(gr + j * 256 + lane * 4);
      float4 sv = *(const float4*)(&sl[j * 256 + lane * 4]);
      acc += gv.x * sv.x + gv.y * sv.y + gv.z * sv.z + gv.w * sv.w;
    }
#pragma unroll
    for (int off = 32; off; off >>= 1) acc += __shfl_xor(acc, off);
    if (lane == 0) g1[b * NH + o] = acc;
  }
}

// ---------------------------------------------------------------------------
// K5: fused MFMA main kernel. Per block: 64 rows (one batch) x 768 cols.
//   A: stage x rows as bf16 in xt[64][776]  (stride 776*2B: <=2-way banks, free)
//   B: g2 = x @ gate_wh^T via mfma_f32_16x16x32_bf16, K-slabs of 32 staged in
//      bsl[768][40] (bsl[n][k] = gate_w[n][NH+k], row-major copy, 16B-aligned)
//   C: elementwise gate -> hs, overwrite xt in place (bf16)
//   D: out = clip(sigmoid(hs @ lin_w^T + lin_b)) via MFMA, reusing bsl (112
//      rows, cols 98..111 zero-padded)
// Wave grid phase B: 8 waves = 2(M:32 rows) x 4(N:192 cols); acc 2x12 frags.
// Fragment maps (16x16x32): A[m=l%16][k=8*(l/16)+i], B[k=8*(l/16)+i][n=l%16],
// D[row=(l>>4)*4+reg][col=l&15] (m89-verified).
// LDS total 160,768 B -> 1 block/CU, 2 waves/SIMD.
// ---------------------------------------------------------------------------
__global__ __launch_bounds__(512, 2) void k_main(
    const float* __restrict__ hidden, const float* __restrict__ gate_w,
    const float* __restrict__ gate_b, const float* __restrict__ lin_w,
    const float* __restrict__ lin_b, const float* __restrict__ sx,
    const float* __restrict__ g1, const int* __restrict__ cue,
    float* __restrict__ out) {
  __shared__ ushort xt[64][776];
  __shared__ ushort bsl[768][40];
  const int t = threadIdx.x;
  const int lane = t & 63, wid = t >> 6;
  const int half = lane >> 4, r16 = lane & 15;
  const int row0 = blockIdx.x * 64;
  const int b = row0 >> 10, s0 = row0 & 1023;

  // ---- phase A: stage hidden rows -> xt (bf16) ----
  const float* src = hidden + (size_t)row0 * NH;
#pragma unroll
  for (int i = 0; i < 24; ++i) {
    int idx = t + 512 * i;  // float4 index, 12288 total (64*192)
    int r = idx / 192, c4 = idx % 192;
    float4 v = *(const float4*)(src + (size_t)r * NH + c4 * 4);
    ushort4 h;
    h.x = f2bf(v.x); h.y = f2bf(v.y); h.z = f2bf(v.z); h.w = f2bf(v.w);
    *(ushort4*)&xt[r][c4 * 4] = h;
  }

  const int wm = wid >> 2, wn = wid & 3;
  f32x4 acc[2][12];
#pragma unroll
  for (int mf = 0; mf < 2; ++mf)
#pragma unroll
    for (int nf = 0; nf < 12; ++nf) acc[mf][nf] = (f32x4)0.f;

  // ---- phase B: g2 GEMM, 24 K-slabs of 32 ----
  for (int slab = 0; slab < 24; ++slab) {
    const int k0 = slab * 32;
#pragma unroll
    for (int i = 0; i < 12; ++i) {
      int idx = t + 512 * i;  // 6144 float4 = 768 rows x 8
      int n = idx >> 3, kq = idx & 7;
      float4 v = *(const float4*)(gate_w + (size_t)n * (2 * NH) + NH + k0 + kq * 4);
      ushort4 h;
      h.x = f2bf(v.x); h.y = f2bf(v.y); h.z = f2bf(v.z); h.w = f2bf(v.w);
      *(ushort4*)&bsl[n][kq * 4] = h;
    }
    __syncthreads();  // also fences phase-A xt writes on slab 0
    short8 a[2];
#pragma unroll
    for (int mf = 0; mf < 2; ++mf)
      a[mf] = *(const short8*)&xt[wm * 32 + mf * 16 + r16][k0 + half * 8];
#pragma unroll
    for (int nf = 0; nf < 12; ++nf) {
      short8 bv = *(const short8*)&bsl[wn * 192 + nf * 16 + r16][half * 8];
      acc[0][nf] = __builtin_amdgcn_mfma_f32_16x16x32_bf16(a[0], bv, acc[0][nf], 0, 0, 0);
      acc[1][nf] = __builtin_amdgcn_mfma_f32_16x16x32_bf16(a[1], bv, acc[1][nf], 0, 0, 0);
    }
    __syncthreads();  // protect bsl overwrite / xt overwrite in phase C
  }

  // ---- phase C: gate elementwise; overwrite xt with hs (bf16) ----
  const int cl = cue[b];
  const int prow = half * 4;
#pragma unroll
  for (int nf = 0; nf < 12; ++nf) {
    int o = wn * 192 + nf * 16 + r16;
    float g1v = g1[b * NH + o];
    float sxv = sx[b * NH + o];
    float gbv = gate_b[o];
#pragma unroll
    for (int mf = 0; mf < 2; ++mf) {
#pragma unroll
      for (int p = 0; p < 4; ++p) {
        int lrow = wm * 32 + mf * 16 + prow + p;
        float x = bf2f(xt[lrow][o]);
        float gl = g1v + acc[mf][nf][p] + gbv;
        float g = 1.f / (1.f + __expf(-gl));
        float fused = g * sxv + (1.f - g) * x;
        float hs = x + (((s0 + lrow) < cl) ? fused : 0.f);
        xt[lrow][o] = f2bf(hs);  // exclusive (row,col) owner
      }
    }
  }
  __syncthreads();

  // ---- phase D: lin head GEMM (N=98 padded to 112), reuse bsl ----
  const int m4 = wid & 3, nh = wid >> 2;
  const int NW = nh ? 3 : 4;  // wave-uniform
  f32x4 acc2[4];
#pragma unroll
  for (int j = 0; j < 4; ++j) acc2[j] = (f32x4)0.f;

  for (int slab = 0; slab < 24; ++slab) {
    const int k0 = slab * 32;
#pragma unroll
    for (int i = 0; i < 2; ++i) {
      int idx = t + 512 * i;  // need 896 float4 = 112 rows x 8
      if (idx < 896) {
        int n = idx >> 3, kq = idx & 7;
        ushort4 h;
        h.x = 0; h.y = 0; h.z = 0; h.w = 0;
        if (n < NP) {
          float4 v = *(const float4*)(lin_w + (size_t)n * NH + k0 + kq * 4);
          h.x = f2bf(v.x); h.y = f2bf(v.y); h.z = f2bf(v.z); h.w = f2bf(v.w);
        }
        *(ushort4*)&bsl[n][kq * 4] = h;
      }
    }
    __syncthreads();
    short8 a = *(const short8*)&xt[m4 * 16 + r16][k0 + half * 8];
#pragma unroll
    for (int j = 0; j < 4; ++j) {
      if (j < NW) {
        short8 bv = *(const short8*)&bsl[(nh * 4 + j) * 16 + r16][half * 8];
        acc2[j] = __builtin_amdgcn_mfma_f32_16x16x32_bf16(a, bv, acc2[j], 0, 0, 0);
      }
    }
    __syncthreads();
  }

  // ---- epilogue: sigmoid + clip + store ----
#pragma unroll
  for (int j = 0; j < 4; ++j) {
    if (j < NW) {
      int col = (nh * 4 + j) * 16 + r16;
      if (col < NP) {
        float lb = lin_b[col];
#pragma unroll
        for (int p = 0; p < 4; ++p) {
          int row = m4 * 16 + prow + p;
          float v = acc2[j][p] + lb;
          v = 1.f / (1.f + __expf(-v));
          v = fminf(fmaxf(v, 1e-7f), 1.f - 1e-7f);
          out[(size_t)(row0 + row) * NP + col] = v;
        }
      }
    }
  }
}

// ---------------------------------------------------------------------------
extern "C" void kernel_launch(void* const* d_in, const int* in_sizes, int n_in,
                              void* d_out, int out_size, void* d_ws, size_t ws_size,
                              hipStream_t stream) {
  const float* hidden = (const float*)d_in[0];
  // d_in[1] = batch_subject_ids: unused by the reference
  const int* mask = (const int*)d_in[2];
  const float* attn_w = (const float*)d_in[3];
  const float* attn_b = (const float*)d_in[4];
  const float* gate_w = (const float*)d_in[5];
  const float* gate_b = (const float*)d_in[6];
  const float* lin_w = (const float*)d_in[7];
  const float* lin_b = (const float*)d_in[8];
  float* out = (float*)d_out;

  // workspace layout (floats): [cue:32int][m:32][l:32][scores:32768][sx:24576][g1:24576]
  float* F = (float*)d_ws;
  int* cue = (int*)F;
  float* m = F + 32;
  float* l = F + 64;
  float* scores = F + 96;
  float* sx = scores + NB * NS;
  float* g1 = sx + NB * NH;

  hipMemsetAsync(sx, 0, NB * NH * sizeof(float), stream);  // K3 accumulates via atomics
  k_scores<<<(NB * NS) / 4, 256, 0, stream>>>(hidden, attn_w, attn_b, scores);
  k_stats<<<NB, 256, 0, stream>>>(mask, scores, cue, m, l);
  k_sx<<<dim3(16, NB), 256, 0, stream>>>(hidden, scores, cue, m, l, sx);
  k_g1<<<NB, 256, 0, stream>>>(sx, gate_w, g1);
  k_main<<<(NB * NS) / 64, 512, 0, stream>>>(hidden, gate_w, gate_b, lin_w, lin_b,
                                             sx, g1, cue, out);
}

// Round 3
// 445.123 us; speedup vs baseline: 7.3903x; 1.1478x over previous
//
#include <hip/hip_runtime.h>
#include <hip/hip_bf16.h>
#include <cstdint>

// Shapes (fixed by the problem)
#define NB 32
#define NS 1024
#define NH 768
#define NP 98

typedef __attribute__((ext_vector_type(8))) short short8;
typedef __attribute__((ext_vector_type(4))) float f32x4;

static __device__ __forceinline__ ushort f2bf(float f) {
  uint32_t u = __builtin_bit_cast(uint32_t, f);
  u += 0x7fff + ((u >> 16) & 1);  // RNE
  return (ushort)(u >> 16);
}
static __device__ __forceinline__ float bf2f(ushort h) {
  uint32_t u = ((uint32_t)h) << 16;
  return __builtin_bit_cast(float, u);
}

// ---------------------------------------------------------------------------
// K0: weight pre-convert (once per call; ws re-poisoned every timed launch).
//   wh_bf[n][k]  = bf16(gate_w[n][NH+k])      (768x768)
//   lin_bf[n][k] = bf16(lin_w[n][k]), rows 98..111 zeroed  (112x768)
// grid 880 blocks x 192 threads (one float4 per thread per row).
// ---------------------------------------------------------------------------
__global__ void k_wprep(const float* __restrict__ gate_w, const float* __restrict__ lin_w,
                        ushort* __restrict__ wh_bf, ushort* __restrict__ lin_bf) {
  int r = blockIdx.x, t = threadIdx.x;
  if (r < NH) {
    float4 v = *(const float4*)(gate_w + (size_t)r * (2 * NH) + NH + t * 4);
    ushort4 h;
    h.x = f2bf(v.x); h.y = f2bf(v.y); h.z = f2bf(v.z); h.w = f2bf(v.w);
    *(ushort4*)&wh_bf[(size_t)r * NH + t * 4] = h;
  } else {
    int n = r - NH;  // 0..111
    ushort4 h; h.x = 0; h.y = 0; h.z = 0; h.w = 0;
    if (n < NP) {
      float4 v = *(const float4*)(lin_w + (size_t)n * NH + t * 4);
      h.x = f2bf(v.x); h.y = f2bf(v.y); h.z = f2bf(v.z); h.w = f2bf(v.w);
    }
    *(ushort4*)&lin_bf[(size_t)n * NH + t * 4] = h;
  }
}

// ---------------------------------------------------------------------------
// K1: scores[b,s] = dot(hidden[b,s,:], attn_w) + attn_b   (one wave per row)
// ---------------------------------------------------------------------------
__global__ void k_scores(const float* __restrict__ hidden, const float* __restrict__ aw,
                         const float* __restrict__ ab, float* __restrict__ scores) {
  int row = blockIdx.x * 4 + (threadIdx.x >> 6);
  int lane = threadIdx.x & 63;
  const float* x = hidden + (size_t)row * NH;
  float acc = 0.f;
#pragma unroll
  for (int i = 0; i < 3; ++i) {
    float4 xv = *(const float4*)(x + i * 256 + lane * 4);
    float4 wv = *(const float4*)(aw + i * 256 + lane * 4);
    acc += xv.x * wv.x + xv.y * wv.y + xv.z * wv.z + xv.w * wv.w;
  }
#pragma unroll
  for (int off = 32; off; off >>= 1) acc += __shfl_xor(acc, off);
  if (lane == 0) scores[row] = acc + ab[0];
}

// ---------------------------------------------------------------------------
// K2: per-batch cue_len, softmax max m[b] and denom l[b] over valid prefix
// ---------------------------------------------------------------------------
__global__ void k_stats(const int* __restrict__ mask, const float* __restrict__ scores,
                        int* __restrict__ cue, float* __restrict__ mout,
                        float* __restrict__ lout) {
  int b = blockIdx.x, t = threadIdx.x;
  int lane = t & 63, w = t >> 6;
  __shared__ float red[4];
  __shared__ int redi[4];
  __shared__ int cue_s;

  int sm = 0;
#pragma unroll
  for (int i = 0; i < 4; ++i) sm += mask[b * NS + t + 256 * i];
#pragma unroll
  for (int off = 32; off; off >>= 1) sm += __shfl_xor(sm, off);
  if (lane == 0) redi[w] = sm;
  __syncthreads();
  if (t == 0) {
    int tot = redi[0] + redi[1] + redi[2] + redi[3];
    tot = min(max(tot, 1), NS);
    cue_s = tot;
    cue[b] = tot;
  }
  __syncthreads();
  int cl = cue_s;

  float mx = -1e30f;
#pragma unroll
  for (int i = 0; i < 4; ++i) {
    int s = t + 256 * i;
    if (s < cl) mx = fmaxf(mx, scores[b * NS + s]);
  }
#pragma unroll
  for (int off = 32; off; off >>= 1) mx = fmaxf(mx, __shfl_xor(mx, off));
  if (lane == 0) red[w] = mx;
  __syncthreads();
  float m = fmaxf(fmaxf(red[0], red[1]), fmaxf(red[2], red[3]));
  __syncthreads();  // red[] reused below

  float sum = 0.f;
#pragma unroll
  for (int i = 0; i < 4; ++i) {
    int s = t + 256 * i;
    if (s < cl) sum += __expf(scores[b * NS + s] - m);
  }
#pragma unroll
  for (int off = 32; off; off >>= 1) sum += __shfl_xor(sum, off);
  if (lane == 0) red[w] = sum;
  __syncthreads();
  if (t == 0) {
    mout[b] = m;
    lout[b] = red[0] + red[1] + red[2] + red[3];
  }
}

// ---------------------------------------------------------------------------
// K3: s_x[b,h] = sum_s attn[b,s] * hidden[b,s,h]  (64-s chunks, atomicAdd)
// grid (16,32) x 192 threads; thread t owns cols 4t..4t+3 (float4 loads).
// ---------------------------------------------------------------------------
__global__ void k_sx(const float* __restrict__ hidden, const float* __restrict__ scores,
                     const int* __restrict__ cue, const float* __restrict__ m,
                     const float* __restrict__ l, float* __restrict__ sx) {
  int b = blockIdx.y, ch = blockIdx.x, t = threadIdx.x;
  int s0 = ch * 64;
  int cl = cue[b];
  if (s0 >= cl) return;  // fully-invalid chunk: contributes 0
  __shared__ float w[64];
  if (t < 64) {
    int s = s0 + t;
    float wv = 0.f;
    if (s < cl) wv = __expf(scores[b * NS + s] - m[b]) / l[b];
    w[t] = wv;
  }
  __syncthreads();
  float4 a; a.x = 0.f; a.y = 0.f; a.z = 0.f; a.w = 0.f;
  const float* base = hidden + ((size_t)(b * NS + s0)) * NH;
  for (int s = 0; s < 64; ++s) {
    float ws = w[s];
    float4 v = *(const float4*)(base + s * NH + t * 4);
    a.x = fmaf(ws, v.x, a.x);
    a.y = fmaf(ws, v.y, a.y);
    a.z = fmaf(ws, v.z, a.z);
    a.w = fmaf(ws, v.w, a.w);
  }
  float* dst = sx + b * NH + t * 4;
  atomicAdd(dst + 0, a.x);
  atomicAdd(dst + 1, a.y);
  atomicAdd(dst + 2, a.z);
  atomicAdd(dst + 3, a.w);
}

// ---------------------------------------------------------------------------
// K4: g1[b,o] = dot(s_x[b,:], gate_w[o, 0:768])  grid (6 ogroups, 32 b)
// ---------------------------------------------------------------------------
__global__ void k_g1(const float* __restrict__ sx, const float* __restrict__ gate_w,
                     float* __restrict__ g1) {
  int b = blockIdx.y, og = blockIdx.x, t = threadIdx.x;
  __shared__ float sl[NH];
  if (t < 192) *(float4*)&sl[t * 4] = *(const float4*)(sx + b * NH + t * 4);
  __syncthreads();
  int w = t >> 6, lane = t & 63;
#pragma unroll 4
  for (int j = 0; j < 32; ++j) {
    int o = og * 128 + w * 32 + j;
    const float* gr = gate_w + (size_t)o * (2 * NH);
    float acc = 0.f;
#pragma unroll
    for (int q = 0; q < 3; ++q) {
      float4 gv = *(const float4*)(gr + q * 256 + lane * 4);
      float4 sv = *(const float4*)(&sl[q * 256 + lane * 4]);
      acc += gv.x * sv.x + gv.y * sv.y + gv.z * sv.z + gv.w * sv.w;
    }
#pragma unroll
    for (int off = 32; off; off >>= 1) acc += __shfl_xor(acc, off);
    if (lane == 0) g1[b * NH + o] = acc;
  }
}

// ---------------------------------------------------------------------------
// K5: fused MFMA main kernel. Per block: 64 rows (one batch) x 768 cols.
//   A: stage hidden rows as bf16 in xt[64][776]
//   B: g2 = x @ wh^T via mfma_f32_16x16x32_bf16; bf16 weight slabs (K=32)
//      staged in bsl[768][40] with register-prefetch pipeline:
//        write regs(slab t)->bsl; sync; issue loads(slab t+1)->regs;
//        MFMA slab t (loads hide under MFMA+ds_read); sync
//   C: elementwise gate -> hs, overwrite xt in place (bf16)
//   D: out = clip(sigmoid(hs @ lin_bf^T + lin_b)), same pipeline, reuse bsl
// Wave decomposition phase B: 8 waves, each 64 rows x 96 cols
//   (A-frags 4, B-frags 6, acc 4x6 f32x4 = 96 VGPR).
// Fragment maps (16x16x32): A[m=l%16][k=8*(l/16)+i], B[k=8*(l/16)+i][n=l%16],
// D[row=(l>>4)*4+reg][col=l&15] (m89-verified).
// LDS 160,768 B -> 1 block/CU. Stride 40 ushort = 80 B: 16B-aligned rows,
// b128 reads spread 8 lanes/bank (= b128 floor, conflict-free).
// ---------------------------------------------------------------------------
__global__ __launch_bounds__(512, 2) void k_main(
    const float* __restrict__ hidden, const ushort* __restrict__ wh_bf,
    const ushort* __restrict__ lin_bf, const float* __restrict__ gate_b,
    const float* __restrict__ lin_b, const float* __restrict__ sx,
    const float* __restrict__ g1, const int* __restrict__ cue,
    float* __restrict__ out) {
  __shared__ ushort xt[64][776];
  __shared__ ushort bsl[768][40];
  const int t = threadIdx.x;
  const int lane = t & 63, wid = t >> 6;
  const int half = lane >> 4, r16 = lane & 15;
  const int row0 = blockIdx.x * 64;
  const int b = row0 >> 10, s0 = row0 & 1023;

  // ---- phase A: stage hidden rows -> xt (bf16) ----
  const float* src = hidden + (size_t)row0 * NH;
#pragma unroll
  for (int i = 0; i < 24; ++i) {
    int idx = t + 512 * i;  // float4 index, 12288 total (64*192)
    int r = idx / 192, c4 = idx % 192;
    float4 v = *(const float4*)(src + (size_t)r * NH + c4 * 4);
    ushort4 h;
    h.x = f2bf(v.x); h.y = f2bf(v.y); h.z = f2bf(v.z); h.w = f2bf(v.w);
    *(ushort4*)&xt[r][c4 * 4] = h;
  }

  f32x4 acc[4][6];
#pragma unroll
  for (int mf = 0; mf < 4; ++mf)
#pragma unroll
    for (int nf = 0; nf < 6; ++nf) acc[mf][nf] = (f32x4)0.f;

  // staging decomposition: slab = 768 n-rows x 32 k of bf16 = 3072 x 16B
  const int sn = t >> 2, skq = t & 3;  // per i: n = sn + 128*i? no: idx layout below
  uint4 pf[6];
  // prologue: load slab 0 (n = idx>>2, kq = idx&3, idx = t + 512*i)
#pragma unroll
  for (int i = 0; i < 6; ++i) {
    int idx = t + 512 * i;
    int n = idx >> 2, kq = idx & 3;
    pf[i] = *(const uint4*)(wh_bf + (size_t)n * NH + kq * 8);
  }

  // ---- phase B: g2 GEMM, 24 K-slabs of 32, reg-prefetch pipeline ----
  for (int slab = 0; slab < 24; ++slab) {
    const int k0 = slab * 32;
#pragma unroll
    for (int i = 0; i < 6; ++i) {
      int idx = t + 512 * i;
      int n = idx >> 2, kq = idx & 3;
      *(uint4*)&bsl[n][kq * 8] = pf[i];
    }
    __syncthreads();  // slab data (and phase-A xt on slab 0) visible
    if (slab < 23) {
      const int k1 = k0 + 32;
#pragma unroll
      for (int i = 0; i < 6; ++i) {
        int idx = t + 512 * i;
        int n = idx >> 2, kq = idx & 3;
        pf[i] = *(const uint4*)(wh_bf + (size_t)n * NH + k1 + kq * 8);
      }
    }
    short8 a[4];
#pragma unroll
    for (int mf = 0; mf < 4; ++mf)
      a[mf] = *(const short8*)&xt[mf * 16 + r16][k0 + half * 8];
#pragma unroll
    for (int nf = 0; nf < 6; ++nf) {
      short8 bv = *(const short8*)&bsl[wid * 96 + nf * 16 + r16][half * 8];
#pragma unroll
      for (int mf = 0; mf < 4; ++mf)
        acc[mf][nf] = __builtin_amdgcn_mfma_f32_16x16x32_bf16(a[mf], bv, acc[mf][nf], 0, 0, 0);
    }
    __syncthreads();  // bsl consumed; safe to overwrite next iter
  }

  // ---- phase C: gate elementwise; overwrite xt with hs (bf16) ----
  const int cl = cue[b];
  const int prow = half * 4;
#pragma unroll
  for (int nf = 0; nf < 6; ++nf) {
    int o = wid * 96 + nf * 16 + r16;
    float g1v = g1[b * NH + o];
    float sxv = sx[b * NH + o];
    float gbv = gate_b[o];
#pragma unroll
    for (int mf = 0; mf < 4; ++mf) {
#pragma unroll
      for (int p = 0; p < 4; ++p) {
        int lrow = mf * 16 + prow + p;
        float x = bf2f(xt[lrow][o]);
        float gl = g1v + acc[mf][nf][p] + gbv;
        float g = 1.f / (1.f + __expf(-gl));
        float fused = g * sxv + (1.f - g) * x;
        float hs = x + (((s0 + lrow) < cl) ? fused : 0.f);
        xt[lrow][o] = f2bf(hs);  // exclusive (row,col) owner
      }
    }
  }
  __syncthreads();

  // ---- phase D: lin head GEMM (N=98 padded to 112), reuse bsl ----
  const int m4 = wid & 3, nh = wid >> 2;
  const int NW = nh ? 3 : 4;  // wave-uniform
  f32x4 acc2[4];
#pragma unroll
  for (int j = 0; j < 4; ++j) acc2[j] = (f32x4)0.f;

  const bool act = t < 448;  // 112 rows x 4 chunks of 16B
  const int nD = t >> 2, kqD = t & 3;
  uint4 pfd;
  if (act) pfd = *(const uint4*)(lin_bf + (size_t)nD * NH + kqD * 8);

  for (int slab = 0; slab < 24; ++slab) {
    const int k0 = slab * 32;
    if (act) *(uint4*)&bsl[nD][kqD * 8] = pfd;
    __syncthreads();
    if (slab < 23 && act)
      pfd = *(const uint4*)(lin_bf + (size_t)nD * NH + k0 + 32 + kqD * 8);
    short8 a = *(const short8*)&xt[m4 * 16 + r16][k0 + half * 8];
#pragma unroll
    for (int j = 0; j < 4; ++j) {
      if (j < NW) {
        short8 bv = *(const short8*)&bsl[(nh * 4 + j) * 16 + r16][half * 8];
        acc2[j] = __builtin_amdgcn_mfma_f32_16x16x32_bf16(a, bv, acc2[j], 0, 0, 0);
      }
    }
    __syncthreads();
  }

  // ---- epilogue: sigmoid + clip + store ----
#pragma unroll
  for (int j = 0; j < 4; ++j) {
    if (j < NW) {
      int col = (nh * 4 + j) * 16 + r16;
      if (col < NP) {
        float lb = lin_b[col];
#pragma unroll
        for (int p = 0; p < 4; ++p) {
          int row = m4 * 16 + prow + p;
          float v = acc2[j][p] + lb;
          v = 1.f / (1.f + __expf(-v));
          v = fminf(fmaxf(v, 1e-7f), 1.f - 1e-7f);
          out[(size_t)(row0 + row) * NP + col] = v;
        }
      }
    }
  }
}

// ---------------------------------------------------------------------------
extern "C" void kernel_launch(void* const* d_in, const int* in_sizes, int n_in,
                              void* d_out, int out_size, void* d_ws, size_t ws_size,
                              hipStream_t stream) {
  const float* hidden = (const float*)d_in[0];
  // d_in[1] = batch_subject_ids: unused by the reference
  const int* mask = (const int*)d_in[2];
  const float* attn_w = (const float*)d_in[3];
  const float* attn_b = (const float*)d_in[4];
  const float* gate_w = (const float*)d_in[5];
  const float* gate_b = (const float*)d_in[6];
  const float* lin_w = (const float*)d_in[7];
  const float* lin_b = (const float*)d_in[8];
  float* out = (float*)d_out;

  // ws layout: f32 region then bf16 weights
  // [cue:32i][m:32][l:32][scores:32768][sx:24576][g1:24576] | wh_bf 768*768 | lin_bf 112*768
  float* F = (float*)d_ws;
  int* cue = (int*)F;
  float* m = F + 32;
  float* l = F + 64;
  float* scores = F + 96;
  float* sx = scores + NB * NS;
  float* g1 = sx + NB * NH;
  ushort* wh_bf = (ushort*)(g1 + NB * NH);
  ushort* lin_bf = wh_bf + (size_t)NH * NH;

  hipMemsetAsync(sx, 0, NB * NH * sizeof(float), stream);  // K3 accumulates via atomics
  k_wprep<<<880, 192, 0, stream>>>(gate_w, lin_w, wh_bf, lin_bf);
  k_scores<<<(NB * NS) / 4, 256, 0, stream>>>(hidden, attn_w, attn_b, scores);
  k_stats<<<NB, 256, 0, stream>>>(mask, scores, cue, m, l);
  k_sx<<<dim3(16, NB), 192, 0, stream>>>(hidden, scores, cue, m, l, sx);
  k_g1<<<dim3(6, NB), 256, 0, stream>>>(sx, gate_w, g1);
  k_main<<<(NB * NS) / 64, 512, 0, stream>>>(hidden, wh_bf, lin_bf, gate_b, lin_b,
                                             sx, g1, cue, out);
}

// Round 5
// 353.259 us; speedup vs baseline: 9.3121x; 1.2600x over previous
//
#include <hip/hip_runtime.h>
#include <hip/hip_bf16.h>
#include <cstdint>

// Shapes (fixed by the problem)
#define NB 32
#define NS 1024
#define NH 768
#define NP 98

typedef __attribute__((ext_vector_type(8))) short short8;
typedef __attribute__((ext_vector_type(4))) float f32x4;

static __device__ __forceinline__ ushort f2bf(float f) {
  uint32_t u = __builtin_bit_cast(uint32_t, f);
  u += 0x7fff + ((u >> 16) & 1);  // RNE
  return (ushort)(u >> 16);
}
static __device__ __forceinline__ float bf2f(ushort h) {
  uint32_t u = ((uint32_t)h) << 16;
  return __builtin_bit_cast(float, u);
}
// async global->LDS 16B (per-lane global src, wave-uniform LDS base + lane*16)
static __device__ __forceinline__ void gload16(const ushort* g, ushort* l) {
  __builtin_amdgcn_global_load_lds((const __attribute__((address_space(1))) uint32_t*)g,
                                   (__attribute__((address_space(3))) uint32_t*)l, 16, 0, 0);
}

// ---------------------------------------------------------------------------
// K0: weight pre-convert. wh_bf[768][768]; lin_bf[128][768] rows 98..127 zero.
// ---------------------------------------------------------------------------
__global__ void k_wprep(const float* __restrict__ gate_w, const float* __restrict__ lin_w,
                        ushort* __restrict__ wh_bf, ushort* __restrict__ lin_bf) {
  int r = blockIdx.x, t = threadIdx.x;
  if (r < NH) {
    float4 v = *(const float4*)(gate_w + (size_t)r * (2 * NH) + NH + t * 4);
    ushort4 h;
    h.x = f2bf(v.x); h.y = f2bf(v.y); h.z = f2bf(v.z); h.w = f2bf(v.w);
    *(ushort4*)&wh_bf[(size_t)r * NH + t * 4] = h;
  } else {
    int n = r - NH;  // 0..127
    ushort4 h; h.x = 0; h.y = 0; h.z = 0; h.w = 0;
    if (n < NP) {
      float4 v = *(const float4*)(lin_w + (size_t)n * NH + t * 4);
      h.x = f2bf(v.x); h.y = f2bf(v.y); h.z = f2bf(v.z); h.w = f2bf(v.w);
    }
    *(ushort4*)&lin_bf[(size_t)n * NH + t * 4] = h;
  }
}

// ---------------------------------------------------------------------------
// K1: fused hidden->bf16 convert + scores. 4 waves/block, 8 rows/wave.
// ---------------------------------------------------------------------------
__global__ void k_prep(const float* __restrict__ hidden, const float* __restrict__ aw,
                       const float* __restrict__ ab, ushort* __restrict__ hid_bf,
                       float* __restrict__ scores) {
  int wid = threadIdx.x >> 6, lane = threadIdx.x & 63;
  int rbase = blockIdx.x * 32 + wid * 8;
  float w0[12];
#pragma unroll
  for (int j = 0; j < 3; ++j) {
    float4 wv = *(const float4*)(aw + j * 256 + lane * 4);
    w0[4 * j] = wv.x; w0[4 * j + 1] = wv.y; w0[4 * j + 2] = wv.z; w0[4 * j + 3] = wv.w;
  }
  float abv = ab[0];
  for (int r = rbase; r < rbase + 8; ++r) {
    const float* row = hidden + (size_t)r * NH;
    float acc = 0.f;
#pragma unroll
    for (int j = 0; j < 3; ++j) {
      float4 v = *(const float4*)(row + j * 256 + lane * 4);
      acc += v.x * w0[4 * j] + v.y * w0[4 * j + 1] + v.z * w0[4 * j + 2] + v.w * w0[4 * j + 3];
      ushort4 h;
      h.x = f2bf(v.x); h.y = f2bf(v.y); h.z = f2bf(v.z); h.w = f2bf(v.w);
      *(ushort4*)&hid_bf[(size_t)r * NH + j * 256 + lane * 4] = h;
    }
#pragma unroll
    for (int off = 32; off; off >>= 1) acc += __shfl_xor(acc, off);
    if (lane == 0) scores[r] = acc + abv;
  }
}

// ---------------------------------------------------------------------------
// K2: per-batch cue_len, softmax max m[b] and denom l[b]
// ---------------------------------------------------------------------------
__global__ void k_stats(const int* __restrict__ mask, const float* __restrict__ scores,
                        int* __restrict__ cue, float* __restrict__ mout,
                        float* __restrict__ lout) {
  int b = blockIdx.x, t = threadIdx.x;
  int lane = t & 63, w = t >> 6;
  __shared__ float red[4];
  __shared__ int redi[4];
  __shared__ int cue_s;

  int sm = 0;
#pragma unroll
  for (int i = 0; i < 4; ++i) sm += mask[b * NS + t + 256 * i];
#pragma unroll
  for (int off = 32; off; off >>= 1) sm += __shfl_xor(sm, off);
  if (lane == 0) redi[w] = sm;
  __syncthreads();
  if (t == 0) {
    int tot = redi[0] + redi[1] + redi[2] + redi[3];
    tot = min(max(tot, 1), NS);
    cue_s = tot;
    cue[b] = tot;
  }
  __syncthreads();
  int cl = cue_s;

  float mx = -1e30f;
#pragma unroll
  for (int i = 0; i < 4; ++i) {
    int s = t + 256 * i;
    if (s < cl) mx = fmaxf(mx, scores[b * NS + s]);
  }
#pragma unroll
  for (int off = 32; off; off >>= 1) mx = fmaxf(mx, __shfl_xor(mx, off));
  if (lane == 0) red[w] = mx;
  __syncthreads();
  float m = fmaxf(fmaxf(red[0], red[1]), fmaxf(red[2], red[3]));
  __syncthreads();

  float sum = 0.f;
#pragma unroll
  for (int i = 0; i < 4; ++i) {
    int s = t + 256 * i;
    if (s < cl) sum += __expf(scores[b * NS + s] - m);
  }
#pragma unroll
  for (int off = 32; off; off >>= 1) sum += __shfl_xor(sum, off);
  if (lane == 0) red[w] = sum;
  __syncthreads();
  if (t == 0) {
    mout[b] = m;
    lout[b] = red[0] + red[1] + red[2] + red[3];
  }
}

// ---------------------------------------------------------------------------
// K3: s_x[b,h] from bf16 hidden (halved traffic). 192 thr: 4 cols each.
// ---------------------------------------------------------------------------
__global__ void k_sx(const ushort* __restrict__ hid_bf, const float* __restrict__ scores,
                     const int* __restrict__ cue, const float* __restrict__ m,
                     const float* __restrict__ l, float* __restrict__ sx) {
  int b = blockIdx.y, ch = blockIdx.x, t = threadIdx.x;
  int s0 = ch * 64;
  int cl = cue[b];
  if (s0 >= cl) return;
  __shared__ float w[64];
  if (t < 64) {
    int s = s0 + t;
    float wv = 0.f;
    if (s < cl) wv = __expf(scores[b * NS + s] - m[b]) / l[b];
    w[t] = wv;
  }
  __syncthreads();
  float4 a; a.x = 0.f; a.y = 0.f; a.z = 0.f; a.w = 0.f;
  const ushort* base = hid_bf + ((size_t)(b * NS + s0)) * NH;
  for (int s = 0; s < 64; ++s) {
    float ws = w[s];
    ushort4 v = *(const ushort4*)(base + s * NH + t * 4);
    a.x = fmaf(ws, bf2f(v.x), a.x);
    a.y = fmaf(ws, bf2f(v.y), a.y);
    a.z = fmaf(ws, bf2f(v.z), a.z);
    a.w = fmaf(ws, bf2f(v.w), a.w);
  }
  float* dst = sx + b * NH + t * 4;
  atomicAdd(dst + 0, a.x);
  atomicAdd(dst + 1, a.y);
  atomicAdd(dst + 2, a.z);
  atomicAdd(dst + 3, a.w);
}

// ---------------------------------------------------------------------------
// K4: g1[b,o] = dot(s_x[b,:], gate_w[o, 0:768])  grid (6 ogroups, 32 b)
// ---------------------------------------------------------------------------
__global__ void k_g1(const float* __restrict__ sx, const float* __restrict__ gate_w,
                     float* __restrict__ g1) {
  int b = blockIdx.y, og = blockIdx.x, t = threadIdx.x;
  __shared__ float sl[NH];
  if (t < 192) *(float4*)&sl[t * 4] = *(const float4*)(sx + b * NH + t * 4);
  __syncthreads();
  int w = t >> 6, lane = t & 63;
#pragma unroll 4
  for (int j = 0; j < 32; ++j) {
    int o = og * 128 + w * 32 + j;
    const float* gr = gate_w + (size_t)o * (2 * NH);
    float acc = 0.f;
#pragma unroll
    for (int q = 0; q < 3; ++q) {
      float4 gv = *(const float4*)(gr + q * 256 + lane * 4);
      float4 sv = *(const float4*)(&sl[q * 256 + lane * 4]);
      acc += gv.x * sv.x + gv.y * sv.y + gv.z * sv.z + gv.w * sv.w;
    }
#pragma unroll
    for (int off = 32; off; off >>= 1) acc += __shfl_xor(acc, off);
    if (lane == 0) g1[b * NH + o] = acc;
  }
}

// ---------------------------------------------------------------------------
// K5: g2 GEMM + gate epilogue -> hs_bf.  m97-style: 128x192 tile, BK=32,
// global_load_lds w16, 2-barrier K-loop, 20KB LDS (multi-block/CU overlap).
// Wave (of 4): 64 rows x 96 cols = 4x6 16x16 frags.
// XCD swizzle: 1024 blocks, xcd=bid&7 owns mt[32*xcd..+31] x all 4 nt,
// ordered nt-inner so each A-panel is L2-reused 4x (A read once from HBM).
// ---------------------------------------------------------------------------
__global__ __launch_bounds__(256, 2) void k_gemm1(
    const ushort* __restrict__ hid_bf, const ushort* __restrict__ wh_bf,
    const float* __restrict__ gate_b, const float* __restrict__ sx,
    const float* __restrict__ g1, const int* __restrict__ cue,
    ushort* __restrict__ hs_bf) {
  __shared__ ushort As[128 * 32];
  __shared__ ushort Bs[192 * 32];
  const int t = threadIdx.x;
  const int lane = t & 63, wid = t >> 6;
  const int half = lane >> 4, r16 = lane & 15;

  const int bid = blockIdx.x;
  const int xcd = bid & 7, i = bid >> 3;
  const int nt = i & 3, mt = xcd * 32 + (i >> 2);
  const int row0 = mt * 128, col0 = nt * 192;

  // staging chunk addresses (advance k0 via +k0 each slab)
  const int c0 = t, c1 = t + 256, c2 = t + 512;
  const ushort* gA0 = hid_bf + (size_t)(row0 + (c0 >> 2)) * NH + (c0 & 3) * 8;
  const ushort* gA1 = hid_bf + (size_t)(row0 + (c1 >> 2)) * NH + (c1 & 3) * 8;
  const ushort* gB0 = wh_bf + (size_t)(col0 + (c0 >> 2)) * NH + (c0 & 3) * 8;
  const ushort* gB1 = wh_bf + (size_t)(col0 + (c1 >> 2)) * NH + (c1 & 3) * 8;
  const ushort* gB2 = wh_bf + (size_t)(col0 + (c2 >> 2)) * NH + (c2 & 3) * 8;
  ushort* lA0 = &As[c0 * 8];
  ushort* lA1 = &As[c1 * 8];
  ushort* lB0 = &Bs[c0 * 8];
  ushort* lB1 = &Bs[c1 * 8];
  ushort* lB2 = &Bs[c2 * 8];

  const int wm = wid >> 1, wn = wid & 1;
  f32x4 acc[4][6];
#pragma unroll
  for (int mf = 0; mf < 4; ++mf)
#pragma unroll
    for (int nf = 0; nf < 6; ++nf) acc[mf][nf] = (f32x4)0.f;

  for (int ks = 0; ks < 24; ++ks) {
    const int k0 = ks * 32;
    gload16(gA0 + k0, lA0);
    gload16(gA1 + k0, lA1);
    gload16(gB0 + k0, lB0);
    gload16(gB1 + k0, lB1);
    gload16(gB2 + k0, lB2);
    __syncthreads();  // drains vmcnt: slab visible
    short8 af[4], bfr[6];
#pragma unroll
    for (int mf = 0; mf < 4; ++mf)
      af[mf] = *(const short8*)&As[(wm * 64 + mf * 16 + r16) * 32 + half * 8];
#pragma unroll
    for (int nf = 0; nf < 6; ++nf)
      bfr[nf] = *(const short8*)&Bs[(wn * 96 + nf * 16 + r16) * 32 + half * 8];
#pragma unroll
    for (int nf = 0; nf < 6; ++nf)
#pragma unroll
      for (int mf = 0; mf < 4; ++mf)
        acc[mf][nf] = __builtin_amdgcn_mfma_f32_16x16x32_bf16(af[mf], bfr[nf], acc[mf][nf], 0, 0, 0);
    __syncthreads();  // protect LDS overwrite next slab
  }

  // gate epilogue
  const int b = mt >> 3;
  const int cl = cue[b];
#pragma unroll
  for (int nf = 0; nf < 6; ++nf) {
    int col = col0 + wn * 96 + nf * 16 + r16;
    float g1v = g1[b * NH + col];
    float sxv = sx[b * NH + col];
    float gbv = gate_b[col];
#pragma unroll
    for (int mf = 0; mf < 4; ++mf) {
#pragma unroll
      for (int p = 0; p < 4; ++p) {
        int grow = row0 + wm * 64 + mf * 16 + half * 4 + p;
        float x = bf2f(hid_bf[(size_t)grow * NH + col]);
        float gl = g1v + acc[mf][nf][p] + gbv;
        float g = 1.f / (1.f + __expf(-gl));
        float fused = g * sxv + (1.f - g) * x;
        float hs = x + (((grow & 1023) < cl) ? fused : 0.f);
        hs_bf[(size_t)grow * NH + col] = f2bf(hs);
      }
    }
  }
}

// ---------------------------------------------------------------------------
// K6: out = clip(sigmoid(hs_bf @ lin_bf^T + lin_b)). 128x112(pad128) tiles,
// BK=32, 256 blocks, wave = 32 rows x 112 cols (2x7 frags).
// ---------------------------------------------------------------------------
__global__ __launch_bounds__(256, 1) void k_gemm2(
    const ushort* __restrict__ hs_bf, const ushort* __restrict__ lin_bf,
    const float* __restrict__ lin_b, float* __restrict__ out) {
  __shared__ ushort As[128 * 32];
  __shared__ ushort Bs[128 * 32];
  const int t = threadIdx.x;
  const int lane = t & 63, wid = t >> 6;
  const int half = lane >> 4, r16 = lane & 15;
  const int row0 = blockIdx.x * 128;

  const int c0 = t, c1 = t + 256;
  const ushort* gA0 = hs_bf + (size_t)(row0 + (c0 >> 2)) * NH + (c0 & 3) * 8;
  const ushort* gA1 = hs_bf + (size_t)(row0 + (c1 >> 2)) * NH + (c1 & 3) * 8;
  const ushort* gB0 = lin_bf + (size_t)(c0 >> 2) * NH + (c0 & 3) * 8;
  const ushort* gB1 = lin_bf + (size_t)(c1 >> 2) * NH + (c1 & 3) * 8;
  ushort* lA0 = &As[c0 * 8];
  ushort* lA1 = &As[c1 * 8];
  ushort* lB0 = &Bs[c0 * 8];
  ushort* lB1 = &Bs[c1 * 8];

  f32x4 acc[2][7];
#pragma unroll
  for (int mf = 0; mf < 2; ++mf)
#pragma unroll
    for (int nf = 0; nf < 7; ++nf) acc[mf][nf] = (f32x4)0.f;

  for (int ks = 0; ks < 24; ++ks) {
    const int k0 = ks * 32;
    gload16(gA0 + k0, lA0);
    gload16(gA1 + k0, lA1);
    gload16(gB0 + k0, lB0);
    gload16(gB1 + k0, lB1);
    __syncthreads();
    short8 af[2], bfr[7];
#pragma unroll
    for (int mf = 0; mf < 2; ++mf)
      af[mf] = *(const short8*)&As[(wid * 32 + mf * 16 + r16) * 32 + half * 8];
#pragma unroll
    for (int nf = 0; nf < 7; ++nf)
      bfr[nf] = *(const short8*)&Bs[(nf * 16 + r16) * 32 + half * 8];
#pragma unroll
    for (int nf = 0; nf < 7; ++nf)
#pragma unroll
      for (int mf = 0; mf < 2; ++mf)
        acc[mf][nf] = __builtin_amdgcn_mfma_f32_16x16x32_bf16(af[mf], bfr[nf], acc[mf][nf], 0, 0, 0);
    __syncthreads();
  }

#pragma unroll
  for (int nf = 0; nf < 7; ++nf) {
    int col = nf * 16 + r16;
    bool valid = col < NP;
    float lbv = valid ? lin_b[col] : 0.f;
#pragma unroll
    for (int mf = 0; mf < 2; ++mf) {
#pragma unroll
      for (int p = 0; p < 4; ++p) {
        int grow = row0 + wid * 32 + mf * 16 + half * 4 + p;
        float v = acc[mf][nf][p] + lbv;
        v = 1.f / (1.f + __expf(-v));
        v = fminf(fmaxf(v, 1e-7f), 1.f - 1e-7f);
        if (valid) out[(size_t)grow * NP + col] = v;
      }
    }
  }
}

// ---------------------------------------------------------------------------
extern "C" void kernel_launch(void* const* d_in, const int* in_sizes, int n_in,
                              void* d_out, int out_size, void* d_ws, size_t ws_size,
                              hipStream_t stream) {
  const float* hidden = (const float*)d_in[0];
  // d_in[1] = batch_subject_ids: unused by the reference
  const int* mask = (const int*)d_in[2];
  const float* attn_w = (const float*)d_in[3];
  const float* attn_b = (const float*)d_in[4];
  const float* gate_w = (const float*)d_in[5];
  const float* gate_b = (const float*)d_in[6];
  const float* lin_w = (const float*)d_in[7];
  const float* lin_b = (const float*)d_in[8];
  float* out = (float*)d_out;

  // ws layout (floats): [cue:32i][m:32][l:32][scores:32768][sx:24576][g1:24576]
  // then (ushort, 16B-aligned): wh_bf[768*768] lin_bf[128*768]
  //                             hid_bf[32768*768] hs_bf[32768*768]  (~103 MB)
  float* F = (float*)d_ws;
  int* cue = (int*)F;
  float* m = F + 32;
  float* l = F + 64;
  float* scores = F + 96;
  float* sx = scores + NB * NS;
  float* g1 = sx + NB * NH;
  ushort* wh_bf = (ushort*)(g1 + NB * NH);
  ushort* lin_bf = wh_bf + (size_t)NH * NH;
  ushort* hid_bf = lin_bf + (size_t)128 * NH;
  ushort* hs_bf = hid_bf + (size_t)NB * NS * NH;

  hipMemsetAsync(sx, 0, NB * NH * sizeof(float), stream);
  k_wprep<<<896, 192, 0, stream>>>(gate_w, lin_w, wh_bf, lin_bf);
  k_prep<<<1024, 256, 0, stream>>>(hidden, attn_w, attn_b, hid_bf, scores);
  k_stats<<<NB, 256, 0, stream>>>(mask, scores, cue, m, l);
  k_sx<<<dim3(16, NB), 192, 0, stream>>>(hid_bf, scores, cue, m, l, sx);
  k_g1<<<dim3(6, NB), 256, 0, stream>>>(sx, gate_w, g1);
  k_gemm1<<<1024, 256, 0, stream>>>(hid_bf, wh_bf, gate_b, sx, g1, cue, hs_bf);
  k_gemm2<<<256, 256, 0, stream>>>(hs_bf, lin_bf, lin_b, out);
}